// Round 3
// baseline (1149.725 us; speedup 1.0000x reference)
//
#include <hip/hip_runtime.h>

typedef __bf16 bf16_t;
typedef __bf16 bf16x8 __attribute__((ext_vector_type(8)));
typedef float  f32x4  __attribute__((ext_vector_type(4)));

#define S_LEN 2048
#define NH    16
#define DH    64
#define DM    1024
#define BATCH 4

static __device__ __forceinline__ f32x4 mfma16(bf16x8 a, bf16x8 b, f32x4 c) {
    return __builtin_amdgcn_mfma_f32_16x16x32_bf16(a, b, c, 0, 0, 0);
}

// load 8 contiguous elements as bf16x8 (fp32 source converts on the fly)
static __device__ __forceinline__ bf16x8 load8(const bf16_t* p) {
    return *(const bf16x8*)p;
}
static __device__ __forceinline__ bf16x8 load8(const float* p) {
    const float4* q = (const float4*)p;
    float4 a = q[0], b = q[1];
    bf16x8 r;
    r[0] = (bf16_t)a.x; r[1] = (bf16_t)a.y; r[2] = (bf16_t)a.z; r[3] = (bf16_t)a.w;
    r[4] = (bf16_t)b.x; r[5] = (bf16_t)b.y; r[6] = (bf16_t)b.z; r[7] = (bf16_t)b.w;
    return r;
}

// ---------------- NN GEMM: C[M][N] = alpha * (A[M][K] . B[K][N]) -------------
// A: fp32 or bf16 (template). B: fp32 row-major [K][N], staged transposed into
// LDS (bf16) so MFMA B-frags read contiguous b128. C: fp32 or bf16 (template).
// Block tile 64x64, BK=32, 4 waves in 2x2, each wave 32x32 (2x2 MFMA frags).
template <typename AT, typename CT>
__global__ __launch_bounds__(256) void gemm_nn(const AT* __restrict__ A,
                                               const float* __restrict__ B,
                                               CT* __restrict__ C,
                                               int M, int N, int K, float alpha) {
    __shared__ __align__(16) bf16_t As[64 * 40];  // [m][k] stride 40 (>=32)
    __shared__ __align__(16) bf16_t Bs[64 * 40];  // [n][k] stride 40 (>=32)
    int tid  = threadIdx.x;
    int wave = tid >> 6, lane = tid & 63;
    int l15  = lane & 15, quad = lane >> 4;
    int wm   = wave >> 1, wn = wave & 1;
    int bm   = blockIdx.x * 64;
    int bn   = blockIdx.y * 64;

    int arow   = tid >> 2;            // 0..63
    int achunk = (tid & 3) << 3;      // 0,8,16,24
    int bk     = tid >> 3;            // 0..31 (k within tile)
    int bn0    = (tid & 7) << 3;      // 0,8,..,56 (n within tile)

    f32x4 acc[2][2] = {};

    for (int k0 = 0; k0 < K; k0 += 32) {
        bf16x8 av = load8(A + (bm + arow) * K + k0 + achunk);
        *(bf16x8*)(As + arow * 40 + achunk) = av;
        bf16x8 bv = load8(B + (k0 + bk) * N + bn + bn0);
#pragma unroll
        for (int i = 0; i < 8; ++i) Bs[(bn0 + i) * 40 + bk] = bv[i];
        __syncthreads();

        bf16x8 af[2], bfr[2];
#pragma unroll
        for (int i = 0; i < 2; ++i)
            af[i] = *(const bf16x8*)(As + (wm * 32 + i * 16 + l15) * 40 + quad * 8);
#pragma unroll
        for (int j = 0; j < 2; ++j)
            bfr[j] = *(const bf16x8*)(Bs + (wn * 32 + j * 16 + l15) * 40 + quad * 8);
#pragma unroll
        for (int i = 0; i < 2; ++i)
#pragma unroll
            for (int j = 0; j < 2; ++j)
                acc[i][j] = mfma16(af[i], bfr[j], acc[i][j]);
        __syncthreads();
    }

    // epilogue: C/D layout col=lane&15, row=quad*4+reg
#pragma unroll
    for (int i = 0; i < 2; ++i) {
#pragma unroll
        for (int r = 0; r < 4; ++r) {
            int row = bm + wm * 32 + i * 16 + quad * 4 + r;
#pragma unroll
            for (int j = 0; j < 2; ++j) {
                int col = bn + wn * 32 + j * 16 + l15;
                C[row * N + col] = (CT)(acc[i][j][r] * alpha);
            }
        }
    }
}

// ---------------- fused attention, one batch ([s][NH*DH] bf16 layout) --------
// one workgroup per (q-tile of 64, h); 4 waves, 16 q-rows each.
// Exact reference mask semantics: score' = score - 1e10 if (pad==0 || key>q)
// (fp32 absorption makes masked entries exactly -1e10, matching the ref).
// All 64 key tiles processed (full-row softmax incl. fully-masked edge case).
// NOTE: ctx may alias Qp — each block reads only its own (rows, head) slice of
// Qp (into registers, at kernel start) and writes only that same slice at end.
__global__ __launch_bounds__(256) void attn_kernel(const bf16_t* __restrict__ Qp,
                                                   const bf16_t* __restrict__ Kp,
                                                   const bf16_t* __restrict__ Vp,
                                                   const int* __restrict__ Kini,
                                                   bf16_t* __restrict__ ctx) {
    __shared__ __align__(16) bf16_t Ks[32 * 72];       // [key][dh] stride 72 (>=64)
    __shared__ __align__(16) bf16_t VsT[64 * 40];      // [dh][key] stride 40 (>=32)
    __shared__ __align__(16) bf16_t Ps[4][16 * 40];    // per-wave P [qrow][key]

    int qt = blockIdx.x, h = blockIdx.y;
    int tid = threadIdx.x, wave = tid >> 6, lane = tid & 63;
    int l15 = lane & 15, quad = lane >> 4;
    int qbase = qt * 64 + wave * 16;

    // Q fragments (A-layout: m=lane&15 -> q-row, k=quad*8+j -> dh)
    const bf16_t* qptr = Qp + (qbase + l15) * DM + h * DH + quad * 8;
    bf16x8 qa0 = *(const bf16x8*)qptr;          // dh 0..31
    bf16x8 qa1 = *(const bf16x8*)(qptr + 32);   // dh 32..63

    f32x4 o[4] = {};                 // O accum, C-layout: o[j] covers dh tile j*16
    float m_[4], l_[4];
#pragma unroll
    for (int r = 0; r < 4; ++r) { m_[r] = -3.0e38f; l_[r] = 0.0f; }

    int skey = tid >> 3, schunk = (tid & 7) << 3;   // Ks staging: 32 keys x 64 dh
    int vkey = tid & 31, vd = (tid >> 5) << 3;      // VsT staging (transposed)

    for (int kt = 0; kt < S_LEN / 32; ++kt) {
        int kb = kt * 32;
        bf16x8 kv = *(const bf16x8*)(Kp + (kb + skey) * DM + h * DH + schunk);
        *(bf16x8*)(Ks + skey * 72 + schunk) = kv;
        bf16x8 vv = *(const bf16x8*)(Vp + (kb + vkey) * DM + h * DH + vd);
#pragma unroll
        for (int i = 0; i < 8; ++i) VsT[(vd + i) * 40 + vkey] = vv[i];
        __syncthreads();

        // QK^T: two 16-key subtiles, contraction over dh=64 (2 mfmas each)
        float sv[2][4];
#pragma unroll
        for (int ks = 0; ks < 2; ++ks) {
            bf16x8 kb0 = *(const bf16x8*)(Ks + (ks * 16 + l15) * 72 + quad * 8);
            bf16x8 kb1 = *(const bf16x8*)(Ks + (ks * 16 + l15) * 72 + 32 + quad * 8);
            f32x4 s = {0.f, 0.f, 0.f, 0.f};
            s = mfma16(qa0, kb0, s);
            s = mfma16(qa1, kb1, s);
            int key = kb + ks * 16 + l15;
            bool padz = (Kini[key] == 0);
#pragma unroll
            for (int r = 0; r < 4; ++r) {
                int q = qbase + quad * 4 + r;
                float val = s[r];                       // q pre-scaled by 1/8
                if (padz || key > q) val -= 1e10f;      // additive mask, exact ref
                sv[ks][r] = val;
            }
        }

        // online softmax (stats reduced over the 16 lanes of each quad group)
#pragma unroll
        for (int r = 0; r < 4; ++r) {
            float mx = fmaxf(sv[0][r], sv[1][r]);
#pragma unroll
            for (int d = 1; d < 16; d <<= 1) mx = fmaxf(mx, __shfl_xor(mx, d));
            float mn = fmaxf(m_[r], mx);
            float al = __expf(m_[r] - mn);
            float p0 = __expf(sv[0][r] - mn);
            float p1 = __expf(sv[1][r] - mn);
            float rs = p0 + p1;
#pragma unroll
            for (int d = 1; d < 16; d <<= 1) rs += __shfl_xor(rs, d);
            l_[r] = l_[r] * al + rs;
            m_[r] = mn;
#pragma unroll
            for (int j = 0; j < 4; ++j) o[j][r] *= al;
            Ps[wave][(quad * 4 + r) * 40 + l15]      = (bf16_t)p0;
            Ps[wave][(quad * 4 + r) * 40 + 16 + l15] = (bf16_t)p1;
        }

        // P back in A-layout (per-wave buffer; same-wave DS ops in order,
        // compiler inserts the lgkmcnt wait for the dependence)
        bf16x8 pa = *(const bf16x8*)(Ps[wave] + l15 * 40 + quad * 8);
#pragma unroll
        for (int j = 0; j < 4; ++j) {
            bf16x8 vb = *(const bf16x8*)(VsT + (j * 16 + l15) * 40 + quad * 8);
            o[j] = mfma16(pa, vb, o[j]);
        }
        __syncthreads();
    }

    // normalize + write ctx[s][h*64+dh]
#pragma unroll
    for (int r = 0; r < 4; ++r) {
        int q = qbase + quad * 4 + r;
        float inv = 1.0f / l_[r];
        bf16_t* cp = ctx + q * DM + h * DH;
#pragma unroll
        for (int j = 0; j < 4; ++j)
            cp[j * 16 + l15] = (bf16_t)(o[j][r] * inv);
    }
}

extern "C" void kernel_launch(void* const* d_in, const int* in_sizes, int n_in,
                              void* d_out, int out_size, void* d_ws, size_t ws_size,
                              hipStream_t stream) {
    // Reference dtypes: embeddings/weights float32, token ids int32, out float32.
    const float* Qe = (const float*)d_in[0];
    const float* Ke = (const float*)d_in[1];
    const float* Ve = (const float*)d_in[2];
    const int* Kini = (const int*)d_in[4];      // Q_ini (d_in[3]) unused by ref
    const float* WQ = (const float*)d_in[5];
    const float* WK = (const float*)d_in[6];
    const float* WV = (const float*)d_in[7];
    const float* WO = (const float*)d_in[8];
    float* out = (float*)d_out;

    // per-batch workspace: Qp, Kp, Vp bf16 (S*DM each = 4 MB); Cx aliases Qp.
    bf16_t* Qp = (bf16_t*)d_ws;
    bf16_t* Kp = Qp + (size_t)S_LEN * DM;
    bf16_t* Vp = Kp + (size_t)S_LEN * DM;
    bf16_t* Cx = Qp;   // alias: see attn_kernel note

    dim3 gg(S_LEN / 64, DM / 64), gb(256);
    dim3 ag(S_LEN / 64, NH);
    for (int b = 0; b < BATCH; ++b) {
        const size_t off = (size_t)b * S_LEN * DM;
        gemm_nn<float, bf16_t><<<gg, gb, 0, stream>>>(Qe + off, WQ, Qp, S_LEN, DM, DM, 0.125f);
        gemm_nn<float, bf16_t><<<gg, gb, 0, stream>>>(Ke + off, WK, Kp, S_LEN, DM, DM, 1.0f);
        gemm_nn<float, bf16_t><<<gg, gb, 0, stream>>>(Ve + off, WV, Vp, S_LEN, DM, DM, 1.0f);
        attn_kernel<<<ag, gb, 0, stream>>>(Qp, Kp, Vp, Kini + (size_t)b * S_LEN, Cx);
        gemm_nn<bf16_t, float><<<gg, gb, 0, stream>>>(Cx, WO, out + off, S_LEN, DM, DM, 1.0f);
    }
}

// Round 4
// 542.319 us; speedup vs baseline: 2.1200x; 2.1200x over previous
//
#include <hip/hip_runtime.h>

typedef __bf16 bf16_t;
typedef __bf16 bf16x8 __attribute__((ext_vector_type(8)));
typedef float  f32x4  __attribute__((ext_vector_type(4)));

#define S_LEN 2048
#define NH    16
#define DH    64
#define DM    1024
#define BATCH 4

static __device__ __forceinline__ f32x4 mfma16(bf16x8 a, bf16x8 b, f32x4 c) {
    return __builtin_amdgcn_mfma_f32_16x16x32_bf16(a, b, c, 0, 0, 0);
}

// async global->LDS, 16B per lane. lds base is wave-uniform; HW adds lane*16.
static __device__ __forceinline__ void gl_lds16(const bf16_t* g, bf16_t* l) {
    __builtin_amdgcn_global_load_lds(
        (const __attribute__((address_space(1))) unsigned int*)g,
        (__attribute__((address_space(3))) unsigned int*)l, 16, 0, 0);
}

// ---------------- fp32 -> bf16 elementwise convert (8 elems/thread) ----------
__global__ __launch_bounds__(256) void cvt_bf16(const float* __restrict__ s,
                                                bf16_t* __restrict__ d, int n) {
    int i = (blockIdx.x * 256 + threadIdx.x) * 8;
    if (i >= n) return;
    const float4* q = (const float4*)(s + i);
    float4 a = q[0], b = q[1];
    bf16x8 r;
    r[0] = (bf16_t)a.x; r[1] = (bf16_t)a.y; r[2] = (bf16_t)a.z; r[3] = (bf16_t)a.w;
    r[4] = (bf16_t)b.x; r[5] = (bf16_t)b.y; r[6] = (bf16_t)b.z; r[7] = (bf16_t)b.w;
    *(bf16x8*)(d + i) = r;
}

// ---------------- weight transpose+convert: Wt[n][k] = scale * W[k][n] -------
__global__ __launch_bounds__(256) void wtrans(const float* __restrict__ W,
                                              bf16_t* __restrict__ Wt, float scale) {
    __shared__ bf16_t tile[32][33];
    int x = threadIdx.x, ty = threadIdx.y;
    int bx = blockIdx.x * 32, by = blockIdx.y * 32;
#pragma unroll
    for (int i = 0; i < 4; ++i) {
        int y = ty * 4 + i;
        tile[y][x] = (bf16_t)(W[(by + y) * DM + bx + x] * scale);
    }
    __syncthreads();
#pragma unroll
    for (int i = 0; i < 4; ++i) {
        int y = ty * 4 + i;
        Wt[(bx + y) * DM + by + x] = tile[x][y];
    }
}

// ---------------- NT GEMM (m97 structure): C = alpha * A[M][K] . Bt[N][K]^T --
// 128x128 tile, BK=32, global_load_lds width-16 staging, 4 waves, 4x4 frags.
template <typename CT>
__global__ __launch_bounds__(256) void gemm_nt_128(const bf16_t* __restrict__ A,
                                                   const bf16_t* __restrict__ Bt,
                                                   CT* __restrict__ C,
                                                   int M, int N, int K, float alpha) {
    __shared__ __align__(16) bf16_t As[128 * 32];  // unpadded: global_load_lds layout
    __shared__ __align__(16) bf16_t Bs[128 * 32];
    int tid = threadIdx.x, wave = tid >> 6, lane = tid & 63;
    int l15 = lane & 15, quad = lane >> 4;
    int wm = wave >> 1, wn = wave & 1;
    int bm = blockIdx.x * 128, bn = blockIdx.y * 128;
    int lrow = lane >> 2, lk = (lane & 3) << 3;

    f32x4 acc[4][4] = {};

    for (int k0 = 0; k0 < K; k0 += 32) {
#pragma unroll
        for (int c = 0; c < 2; ++c) {
            int r = wave * 32 + c * 16 + lrow;            // tile row this lane fetches
            gl_lds16(A  + (size_t)(bm + r) * K + k0 + lk, As + (wave * 2 + c) * 512);
            gl_lds16(Bt + (size_t)(bn + r) * K + k0 + lk, Bs + (wave * 2 + c) * 512);
        }
        __syncthreads();   // compiler drains vmcnt before s_barrier

        bf16x8 af[4], bfr[4];
#pragma unroll
        for (int i = 0; i < 4; ++i)
            af[i] = *(const bf16x8*)(As + (wm * 64 + i * 16 + l15) * 32 + quad * 8);
#pragma unroll
        for (int j = 0; j < 4; ++j)
            bfr[j] = *(const bf16x8*)(Bs + (wn * 64 + j * 16 + l15) * 32 + quad * 8);
#pragma unroll
        for (int i = 0; i < 4; ++i)
#pragma unroll
            for (int j = 0; j < 4; ++j)
                acc[i][j] = mfma16(af[i], bfr[j], acc[i][j]);
        __syncthreads();
    }

#pragma unroll
    for (int i = 0; i < 4; ++i)
#pragma unroll
        for (int r = 0; r < 4; ++r) {
            int row = bm + wm * 64 + i * 16 + quad * 4 + r;
#pragma unroll
            for (int j = 0; j < 4; ++j)
                C[(size_t)row * N + bn + wn * 64 + j * 16 + l15] =
                    (CT)(acc[i][j][r] * alpha);
        }
}

// ---------------- per-batch V column mean (for fully-masked-row fallback) ----
__global__ __launch_bounds__(256) void vmean_kernel(const bf16_t* __restrict__ Vp,
                                                    float* __restrict__ Vm) {
    __shared__ float red[4][64];
    int z = blockIdx.y;
    int c = blockIdx.x * 64 + (threadIdx.x & 63);
    int rg = threadIdx.x >> 6;
    const bf16_t* p = Vp + (size_t)z * S_LEN * DM + (size_t)rg * (S_LEN / 4) * DM + c;
    float s = 0.f;
    for (int r = 0; r < S_LEN / 4; ++r) s += (float)p[(size_t)r * DM];
    red[rg][threadIdx.x & 63] = s;
    __syncthreads();
    if (threadIdx.x < 64) {
        float t = red[0][threadIdx.x] + red[1][threadIdx.x] +
                  red[2][threadIdx.x] + red[3][threadIdx.x];
        Vm[z * DM + blockIdx.x * 64 + threadIdx.x] = t * (1.0f / S_LEN);
    }
}

// ---------------- fused attention, causal-skipped, 64-key tiles --------------
// grid (S/64, NH, nb). Exact ref mask: score - 1e10 if (pad==0 || key>q); masked
// entries are exactly -1e10 in fp32. Causal skip is exact for any row with >=1
// unmasked key (exp underflows to 0 / alpha-rescale zeroes bogus prefix). Rows
// with NO unmasked key reproduce the ref's uniform-softmax via Vmean fallback.
// ctx may alias Qp: each block reads only its own (rows x head) slice into regs
// at start and writes only that same slice at the end.
__global__ __launch_bounds__(256) void attn_kernel(const bf16_t* __restrict__ Qp,
                                                   const bf16_t* __restrict__ Kp,
                                                   const bf16_t* __restrict__ Vp,
                                                   const int* __restrict__ Kini,
                                                   const float* __restrict__ Vmean,
                                                   bf16_t* __restrict__ ctx) {
    __shared__ __align__(16) bf16_t Ks[64 * 72];     // [key][dh], stride 72
    __shared__ __align__(16) bf16_t VsT[64 * 72];    // [dh][key], stride 72
    __shared__ __align__(16) bf16_t Ps[4][16 * 72];  // per-wave P [qrow][key]

    int qt = blockIdx.x, h = blockIdx.y, z = blockIdx.z;
    int tid = threadIdx.x, wave = tid >> 6, lane = tid & 63;
    int l15 = lane & 15, quad = lane >> 4;
    int qbase = qt * 64 + wave * 16;
    size_t rowz = (size_t)z * S_LEN;

    const bf16_t* qptr = Qp + (rowz + qbase + l15) * DM + h * DH + quad * 8;
    bf16x8 qa0 = *(const bf16x8*)qptr;
    bf16x8 qa1 = *(const bf16x8*)(qptr + 32);

    f32x4 o[4] = {};
    float m_[4], l_[4];
#pragma unroll
    for (int r = 0; r < 4; ++r) { m_[r] = -3.0e38f; l_[r] = 0.0f; }

    int skey = tid >> 2, sch = (tid & 3) << 4;   // K staging: 64 keys x 64 dh
    int vkey = tid & 63, vdb = (tid >> 6) << 4;  // V staging (transposed)

    int ntiles = qt + 1;                         // causal: only kb <= q_max
    for (int kt = 0; kt < ntiles; ++kt) {
        int kb = kt * 64;
        const bf16_t* kg = Kp + (rowz + kb + skey) * DM + h * DH + sch;
        *(bf16x8*)(Ks + skey * 72 + sch)     = *(const bf16x8*)kg;
        *(bf16x8*)(Ks + skey * 72 + sch + 8) = *(const bf16x8*)(kg + 8);
        const bf16_t* vg = Vp + (rowz + kb + vkey) * DM + h * DH + vdb;
        bf16x8 v0 = *(const bf16x8*)vg;
        bf16x8 v1 = *(const bf16x8*)(vg + 8);
#pragma unroll
        for (int i = 0; i < 8; ++i) VsT[(vdb + i) * 72 + vkey]     = v0[i];
#pragma unroll
        for (int i = 0; i < 8; ++i) VsT[(vdb + 8 + i) * 72 + vkey] = v1[i];
        __syncthreads();

        float sv[4][4];
#pragma unroll
        for (int ks = 0; ks < 4; ++ks) {
            bf16x8 kf0 = *(const bf16x8*)(Ks + (ks * 16 + l15) * 72 + quad * 8);
            bf16x8 kf1 = *(const bf16x8*)(Ks + (ks * 16 + l15) * 72 + 32 + quad * 8);
            f32x4 s = {0.f, 0.f, 0.f, 0.f};
            s = mfma16(qa0, kf0, s);
            s = mfma16(qa1, kf1, s);
            int key = kb + ks * 16 + l15;
            bool padz = (Kini[rowz + key] == 0);
#pragma unroll
            for (int r = 0; r < 4; ++r) {
                int q = qbase + quad * 4 + r;
                float val = s[r];
                if (padz || key > q) val -= 1e10f;
                sv[ks][r] = val;
            }
        }

#pragma unroll
        for (int r = 0; r < 4; ++r) {
            float mx = fmaxf(fmaxf(sv[0][r], sv[1][r]), fmaxf(sv[2][r], sv[3][r]));
#pragma unroll
            for (int d = 1; d < 16; d <<= 1) mx = fmaxf(mx, __shfl_xor(mx, d));
            float mn = fmaxf(m_[r], mx);
            float al = __expf(m_[r] - mn);
            float p0 = __expf(sv[0][r] - mn), p1 = __expf(sv[1][r] - mn);
            float p2 = __expf(sv[2][r] - mn), p3 = __expf(sv[3][r] - mn);
            float rs = (p0 + p1) + (p2 + p3);
#pragma unroll
            for (int d = 1; d < 16; d <<= 1) rs += __shfl_xor(rs, d);
            l_[r] = l_[r] * al + rs;
            m_[r] = mn;
#pragma unroll
            for (int j = 0; j < 4; ++j) o[j][r] *= al;
            int pr = (quad * 4 + r) * 72;
            Ps[wave][pr + l15]      = (bf16_t)p0;
            Ps[wave][pr + 16 + l15] = (bf16_t)p1;
            Ps[wave][pr + 32 + l15] = (bf16_t)p2;
            Ps[wave][pr + 48 + l15] = (bf16_t)p3;
        }

        // P (C-layout) -> A-layout via per-wave LDS round-trip
        bf16x8 pa0 = *(const bf16x8*)(Ps[wave] + l15 * 72 + quad * 8);
        bf16x8 pa1 = *(const bf16x8*)(Ps[wave] + l15 * 72 + 32 + quad * 8);
#pragma unroll
        for (int j = 0; j < 4; ++j) {
            bf16x8 vb0 = *(const bf16x8*)(VsT + (j * 16 + l15) * 72 + quad * 8);
            bf16x8 vb1 = *(const bf16x8*)(VsT + (j * 16 + l15) * 72 + 32 + quad * 8);
            o[j] = mfma16(pa0, vb0, o[j]);
            o[j] = mfma16(pa1, vb1, o[j]);
        }
        __syncthreads();
    }

#pragma unroll
    for (int r = 0; r < 4; ++r) {
        int q = qbase + quad * 4 + r;
        float inv = 1.0f / l_[r];
        bf16_t* cp = ctx + (rowz + q) * DM + h * DH;
        if (m_[r] < -1e9f) {  // fully-masked row: ref softmax is uniform / 2048
            const float* vm = Vmean + z * DM + h * DH;
#pragma unroll
            for (int j = 0; j < 4; ++j) cp[j * 16 + l15] = (bf16_t)vm[j * 16 + l15];
        } else {
#pragma unroll
            for (int j = 0; j < 4; ++j) cp[j * 16 + l15] = (bf16_t)(o[j][r] * inv);
        }
    }
}

extern "C" void kernel_launch(void* const* d_in, const int* in_sizes, int n_in,
                              void* d_out, int out_size, void* d_ws, size_t ws_size,
                              hipStream_t stream) {
    const float* Qe = (const float*)d_in[0];
    const float* Ke = (const float*)d_in[1];
    const float* Ve = (const float*)d_in[2];
    const int* Kini = (const int*)d_in[4];
    const float* WQ = (const float*)d_in[5];
    const float* WK = (const float*)d_in[6];
    const float* WV = (const float*)d_in[7];
    const float* WO = (const float*)d_in[8];
    float* out = (float*)d_out;

    const size_t EMB = (size_t)BATCH * S_LEN * DM;   // 8M elems
    const size_t SB  = (size_t)S_LEN * DM;           // 2M elems
    const size_t WSZ = (size_t)DM * DM;              // 1M elems
    const size_t need_full = (6 * EMB + 4 * WSZ) * sizeof(bf16_t)
                           + (size_t)BATCH * DM * sizeof(float);

    dim3 tb32(32, 8), tg32(32, 32);

    if (ws_size >= need_full) {
        // ---- full-batch path (M = 8192) ----
        bf16_t* Qb  = (bf16_t*)d_ws;
        bf16_t* Kb  = Qb + EMB;
        bf16_t* Vb  = Kb + EMB;
        bf16_t* WQt = Vb + EMB;
        bf16_t* WKt = WQt + WSZ;
        bf16_t* WVt = WKt + WSZ;
        bf16_t* WOt = WVt + WSZ;
        bf16_t* Qp  = WOt + WSZ;
        bf16_t* Kp  = Qp + EMB;
        bf16_t* Vp  = Kp + EMB;
        float*  Vm  = (float*)(Vp + EMB);
        bf16_t* Cx  = Qp;   // alias, block-disjoint (see attn_kernel)

        int cg = (int)(EMB / (8 * 256));
        cvt_bf16<<<cg, 256, 0, stream>>>(Qe, Qb, (int)EMB);
        cvt_bf16<<<cg, 256, 0, stream>>>(Ke, Kb, (int)EMB);
        cvt_bf16<<<cg, 256, 0, stream>>>(Ve, Vb, (int)EMB);
        wtrans<<<tg32, tb32, 0, stream>>>(WQ, WQt, 0.125f);  // fold 1/sqrt(dh)
        wtrans<<<tg32, tb32, 0, stream>>>(WK, WKt, 1.0f);
        wtrans<<<tg32, tb32, 0, stream>>>(WV, WVt, 1.0f);
        wtrans<<<tg32, tb32, 0, stream>>>(WO, WOt, 1.0f);

        dim3 gg(8192 / 128, DM / 128);
        gemm_nt_128<bf16_t><<<gg, 256, 0, stream>>>(Qb, WQt, Qp, 8192, DM, DM, 1.0f);
        gemm_nt_128<bf16_t><<<gg, 256, 0, stream>>>(Kb, WKt, Kp, 8192, DM, DM, 1.0f);
        gemm_nt_128<bf16_t><<<gg, 256, 0, stream>>>(Vb, WVt, Vp, 8192, DM, DM, 1.0f);

        vmean_kernel<<<dim3(DM / 64, BATCH), 256, 0, stream>>>(Vp, Vm);
        attn_kernel<<<dim3(S_LEN / 64, NH, BATCH), 256, 0, stream>>>(Qp, Kp, Vp, Kini, Vm, Cx);

        gemm_nt_128<float><<<gg, 256, 0, stream>>>(Cx, WOt, out, 8192, DM, DM, 1.0f);
    } else {
        // ---- per-batch fallback (M = 2048, ~34 MB workspace) ----
        bf16_t* Qb  = (bf16_t*)d_ws;
        bf16_t* Kb  = Qb + SB;
        bf16_t* Vb  = Kb + SB;
        bf16_t* WQt = Vb + SB;
        bf16_t* WKt = WQt + WSZ;
        bf16_t* WVt = WKt + WSZ;
        bf16_t* WOt = WVt + WSZ;
        bf16_t* Qp  = WOt + WSZ;
        bf16_t* Kp  = Qp + SB;
        bf16_t* Vp  = Kp + SB;
        float*  Vm  = (float*)(Vp + SB);
        bf16_t* Cx  = Qp;

        wtrans<<<tg32, tb32, 0, stream>>>(WQ, WQt, 0.125f);
        wtrans<<<tg32, tb32, 0, stream>>>(WK, WKt, 1.0f);
        wtrans<<<tg32, tb32, 0, stream>>>(WV, WVt, 1.0f);
        wtrans<<<tg32, tb32, 0, stream>>>(WO, WOt, 1.0f);

        int cg = (int)(SB / (8 * 256));
        dim3 gg(2048 / 128, DM / 128);
        for (int b = 0; b < BATCH; ++b) {
            const size_t off = (size_t)b * SB;
            cvt_bf16<<<cg, 256, 0, stream>>>(Qe + off, Qb, (int)SB);
            cvt_bf16<<<cg, 256, 0, stream>>>(Ke + off, Kb, (int)SB);
            cvt_bf16<<<cg, 256, 0, stream>>>(Ve + off, Vb, (int)SB);
            gemm_nt_128<bf16_t><<<gg, 256, 0, stream>>>(Qb, WQt, Qp, 2048, DM, DM, 1.0f);
            gemm_nt_128<bf16_t><<<gg, 256, 0, stream>>>(Kb, WKt, Kp, 2048, DM, DM, 1.0f);
            gemm_nt_128<bf16_t><<<gg, 256, 0, stream>>>(Vb, WVt, Vp, 2048, DM, DM, 1.0f);
            vmean_kernel<<<dim3(DM / 64, 1), 256, 0, stream>>>(Vp, Vm);
            attn_kernel<<<dim3(S_LEN / 64, NH, 1), 256, 0, stream>>>(
                Qp, Kp, Vp, Kini + (size_t)b * S_LEN, Vm, Cx);
            gemm_nt_128<float><<<gg, 256, 0, stream>>>(Cx, WOt, out + off, 2048, DM, DM, 1.0f);
        }
    }
}